// Round 8
// baseline (12694.141 us; speedup 1.0000x reference)
//
#include <hip/hip_runtime.h>
#include <hip/hip_bf16.h>

#define NN 10000      // nodes
#define NE 160000     // edges
#define TS 32         // timesteps
#define HID 256
#define NFEAT 192
#define TTEACH 24

typedef unsigned short u16;
typedef unsigned int u32;
typedef __attribute__((ext_vector_type(8))) short bf16x8;
typedef __attribute__((ext_vector_type(4))) float f32x4;

__device__ __forceinline__ float bf2f(u16 u){
    u32 v = ((u32)u) << 16;
    union { u32 i; float f; } c; c.i = v; return c.f;
}
__device__ __forceinline__ u16 f2bf(float f){
    union { float f; u32 i; } c; c.f = f;
    u32 i = c.i;
    u32 lsb = (i >> 16) & 1u;
    i += 0x7fffu + lsb;
    return (u16)(i >> 16);
}

__global__ void fill_f32(float* p, float v, int n){
    int i = blockIdx.x * 256 + threadIdx.x;
    if (i < n) p[i] = v;
}
__global__ void fill_i32(int* p, int v, int n){
    int i = blockIdx.x * 256 + threadIdx.x;
    if (i < n) p[i] = v;
}
__global__ void copy_i32(const int* __restrict__ a, int* __restrict__ b, int n){
    int i = blockIdx.x * 256 + threadIdx.x;
    if (i < n) b[i] = a[i];
}

// ---------- runtime dtype detection ----------
__global__ void detect_f32(const u16* __restrict__ zraw, int* __restrict__ flag){
    int c = 0;
    for (int i = 0; i < 128; i++) if (zraw[2*i] >= 0x4000) c++;
    *flag = (c > 8) ? 1 : 0;
}
__global__ void conv_f32(const void* __restrict__ in, float* __restrict__ outp,
                         int n, const int* __restrict__ flag){
    int i = blockIdx.x * 256 + threadIdx.x;
    if (i >= n) return;
    if (*flag) outp[i] = ((const float*)in)[i];
    else       outp[i] = bf2f(((const u16*)in)[i]);
}
__global__ void detect_i64(const int* __restrict__ ei_raw, int* __restrict__ flag){
    int zz = 0;
    #pragma unroll
    for (int i = 0; i < 32; i++) zz |= ei_raw[2*i + 1];
    *flag = (zz == 0) ? 1 : 0;
}
__global__ void copy_edges(const int* __restrict__ ei_raw, const int* __restrict__ flag,
                           int* __restrict__ src, int* __restrict__ dst){
    int e = blockIdx.x * 256 + threadIdx.x;
    if (e >= NE) return;
    int st = (*flag) ? 2 : 1;
    src[e] = ei_raw[(size_t)e * st];
    dst[e] = ei_raw[((size_t)NE + e) * st];
}

__global__ void degree_k(const int* __restrict__ dst, int* __restrict__ cnt, int n){
    int e = blockIdx.x * 256 + threadIdx.x;
    if (e < n) atomicAdd(&cnt[dst[e]], 1);
}
__global__ void invcnt_k(const int* __restrict__ cnt, float* __restrict__ inv, int n){
    int i = blockIdx.x * 256 + threadIdx.x;
    if (i < n) inv[i] = 1.0f / fmaxf((float)cnt[i], 1.0f);
}

// exclusive scan of cnt[10000] -> binoff[10000], single block 1024 threads
__global__ void scan_k(const int* __restrict__ cnt, int* __restrict__ binoff){
    __shared__ int ps[1024];
    int t = threadIdx.x;
    int s = 0;
    if (t < 1000)
        for (int i = 0; i < 10; i++) s += cnt[t*10 + i];
    ps[t] = s;
    __syncthreads();
    for (int ofs = 1; ofs < 1024; ofs <<= 1){
        int v = (t >= ofs) ? ps[t - ofs] : 0;
        __syncthreads();
        ps[t] += v;
        __syncthreads();
    }
    if (t < 1000){
        int run = (t == 0) ? 0 : ps[t-1];
        for (int i = 0; i < 10; i++){
            binoff[t*10 + i] = run;
            run += cnt[t*10 + i];
        }
    }
}
// scatter edges into dst-sorted order; builds sorted src/dst and z planes
__global__ void scatter_k(const int* __restrict__ src32, const int* __restrict__ dst32,
                          const float* __restrict__ zc, int* __restrict__ cur,
                          int* __restrict__ srcS, int* __restrict__ dstS,
                          float* __restrict__ zS){
    int e = blockIdx.x * 256 + threadIdx.x;
    if (e >= NE) return;
    int d = dst32[e];
    int pos = atomicAdd(&cur[d], 1);
    srcS[pos] = src32[e];
    dstS[pos] = d;
    zS[pos]        = zc[(size_t)e*4 + 1];
    zS[NE + pos]   = zc[(size_t)e*4 + 2];
    zS[2*NE + pos] = zc[(size_t)e*4 + 3];
}

// WfT[n][k] = Wf[k][n] bf16  (Wf: [256][192])
__global__ void build_wft(const float* __restrict__ Wfc, u16* __restrict__ WfT){
    int idx = blockIdx.x * 256 + threadIdx.x;
    if (idx < 256 * 192){
        int k = idx / 192, n = idx % 192;
        WfT[(size_t)n * 256 + k] = f2bf(Wfc[idx]);
    }
}
// W1T[n][k] bf16, n in [0,1536): kblk=n>>9, part=(n>>8)&1, c=n&255; k in [0,192)
__global__ void build_w1t(const float* __restrict__ W1c, u16* __restrict__ W1T){
    int idx = blockIdx.x * 256 + threadIdx.x;
    if (idx < 1536 * 192){
        int n = idx / 192, k = idx % 192;
        int kblk = n >> 9, part = (n >> 8) & 1, c = n & 255;
        W1T[idx] = f2bf(W1c[(size_t)kblk * (384*256) + (size_t)(part*192 + k) * 256 + c]);
    }
}
__global__ void conv_bf16(const float* __restrict__ in, u16* __restrict__ outp, int n){
    int i = blockIdx.x * 256 + threadIdx.x;
    if (i < n) outp[i] = f2bf(in[i]);
}
// W2T[n][k] = W2[k][n] bf16; W2 flat [768][256] fp32
__global__ void build_w2t(const float* __restrict__ W2c, u16* __restrict__ W2T){
    int idx = blockIdx.x * 256 + threadIdx.x;
    if (idx < 768 * 256){
        int k = idx / 256, n = idx % 256;
        W2T[(size_t)n * 768 + k] = f2bf(W2c[idx]);
    }
}
// m16 = bf16(m_acc * inv); also re-zeros m_acc for the next step's atomics
__global__ void mscale_k(float* __restrict__ m_acc, const float* __restrict__ inv,
                         u16* __restrict__ m16){
    int idx = blockIdx.x * 256 + threadIdx.x;
    if (idx < NN * HID){
        m16[idx] = f2bf(m_acc[idx] * inv[idx >> 8]);
        m_acc[idx] = 0.f;
    }
}

// ---------------- MFMA node GEMM ----------------
// C[M,N] = epi(A16[M,K] @ BT16[N,K]^T + bias)
// MODE 0: +bias, relu, out bf16 | MODE 1: +b1 if part==0, out bf16 | MODE 2: +bias, out fp32
template<int MODE>
__global__ __launch_bounds__(256, 2) void gemm_mfma(
    const u16* __restrict__ A16, const u16* __restrict__ BT16,
    const float* __restrict__ bias, float* __restrict__ Cf, u16* __restrict__ Cb,
    int M, int Kd, int Nd)
{
    __shared__ __align__(16) u16 Alds[256 * 40];
    __shared__ __align__(16) u16 Blds[64 * 40];
    const int tid = threadIdx.x;
    const int m0 = blockIdx.x * 256;
    const int n0 = blockIdx.y * 64;
    const int wave = tid >> 6, lane = tid & 63;
    const int quad = lane >> 4, l16 = lane & 15;

    const f32x4 zero4 = {0.f, 0.f, 0.f, 0.f};
    f32x4 acc[4][4];
    #pragma unroll
    for (int r=0;r<4;r++)
        #pragma unroll
        for (int c=0;c<4;c++) acc[r][c] = zero4;

    const int arow = m0 + tid;
    const u16* ap = &A16[(size_t)arow * Kd];
    const int bn = tid >> 2, bseg = tid & 3;
    const u16* bp = &BT16[(size_t)(n0 + bn) * Kd + bseg * 8];

    for (int k0 = 0; k0 < Kd; k0 += 32){
        if (arow < M){
            const uint4* q = reinterpret_cast<const uint4*>(ap + k0);
            uint4 v0 = q[0], v1 = q[1], v2 = q[2], v3 = q[3];
            *reinterpret_cast<uint4*>(&Alds[tid * 40])      = v0;
            *reinterpret_cast<uint4*>(&Alds[tid * 40 + 8])  = v1;
            *reinterpret_cast<uint4*>(&Alds[tid * 40 + 16]) = v2;
            *reinterpret_cast<uint4*>(&Alds[tid * 40 + 24]) = v3;
        } else {
            uint4 zz = {0,0,0,0};
            #pragma unroll
            for (int s=0;s<4;s++)
                *reinterpret_cast<uint4*>(&Alds[tid * 40 + s*8]) = zz;
        }
        {
            uint4 v = *reinterpret_cast<const uint4*>(bp + k0);
            *reinterpret_cast<uint4*>(&Blds[bn * 40 + bseg * 8]) = v;
        }
        __syncthreads();
        bf16x8 af[4], bfr[4];
        #pragma unroll
        for (int r=0;r<4;r++)
            af[r] = *reinterpret_cast<const bf16x8*>(&Alds[(wave*64 + r*16 + l16) * 40 + quad * 8]);
        #pragma unroll
        for (int c=0;c<4;c++)
            bfr[c] = *reinterpret_cast<const bf16x8*>(&Blds[(c*16 + l16) * 40 + quad * 8]);
        #pragma unroll
        for (int r=0;r<4;r++)
            #pragma unroll
            for (int c=0;c<4;c++)
                acc[r][c] = __builtin_amdgcn_mfma_f32_16x16x32_bf16(af[r], bfr[c], acc[r][c], 0, 0, 0);
        __syncthreads();
    }
    #pragma unroll
    for (int c=0;c<4;c++){
        int col = n0 + c*16 + l16;
        float bv = 0.f;
        if (MODE == 0 || MODE == 2) bv = bias[col];
        if (MODE == 1){
            int part = (col >> 8) & 1;
            if (part == 0) bv = bias[(col >> 9) * 256 + (col & 255)];
        }
        #pragma unroll
        for (int r=0;r<4;r++){
            #pragma unroll
            for (int reg=0;reg<4;reg++){
                int row = m0 + wave*64 + r*16 + quad*4 + reg;
                if (row >= M) continue;
                float v = acc[r][c][reg] + bv;
                if (MODE == 0) v = fmaxf(v, 0.f);
                if (MODE == 2) Cf[(size_t)row * Nd + col] = v;
                else           Cb[(size_t)row * Nd + col] = f2bf(v);
            }
        }
    }
}

// MFMA edge kernel on dst-sorted edges: 64 edges x 256 cols per block, K=768.
// LDS: stg aliases Alds+Blds (disjoint lifetimes). Register prefetch double-buffer
// overlaps next iter's global loads (random gather ~200-400cy L2 latency) with MFMA.
__global__ __launch_bounds__(256, 4) void edge_mfma(
    const u16* __restrict__ AB16, const u16* __restrict__ W2T,
    const float* __restrict__ b2, const float* __restrict__ zS,
    const int* __restrict__ srcS, const int* __restrict__ dstS,
    float* __restrict__ m_acc)
{
    __shared__ __align__(16) char smem[33280];      // max(Alds 5120 + Blds 20480, stg 33280)
    u16*   Alds = (u16*)smem;                        // [64 rows][40 u16]
    u16*   Blds = (u16*)(smem + 5120);               // [256 rows][40 u16]
    float* stg  = (float*)smem;                      // [4][32][65] epilogue alias
    __shared__ float zc3[3][64];
    __shared__ int dstc[64], srcc[64];
    const int tid = threadIdx.x;
    const int eb = blockIdx.x * 64;

    if (tid < 64){
        srcc[tid] = srcS[eb + tid];
        dstc[tid] = dstS[eb + tid];
    }
    int tz = tid - 64;
    if (tz >= 0 && tz < 192){
        int g = tz / 64, e = tz % 64;
        zc3[g][e] = zS[(size_t)g * NE + eb + e];
    }
    __syncthreads();

    const int wave = tid >> 6, lane = tid & 63;
    const int quad = lane >> 4, l16 = lane & 15;
    const int est = tid >> 2, seg = tid & 3;

    const f32x4 zero4 = {0.f, 0.f, 0.f, 0.f};
    f32x4 acc[4][4];
    #pragma unroll
    for (int r=0;r<4;r++)
        #pragma unroll
        for (int c=0;c<4;c++) acc[r][c] = zero4;

    const int d = dstc[est], s = srcc[est];
    const u16* paB = &AB16[(size_t)d * 1536];         // + g*512 + j0
    const u16* pbB = &AB16[(size_t)s * 1536 + 256];
    const int bn = tid >> 2;
    const u16* bwB = &W2T[(size_t)bn * 768 + seg * 8];// rows bn + i*64

    // prefetch iter 0
    uint4 pa = *reinterpret_cast<const uint4*>(&paB[seg * 8]);
    uint4 pb = *reinterpret_cast<const uint4*>(&pbB[seg * 8]);
    uint4 pw[4];
    #pragma unroll
    for (int i=0;i<4;i++)
        pw[i] = *reinterpret_cast<const uint4*>(&bwB[(size_t)i * 64 * 768]);

    for (int kc = 0; kc < 768; kc += 32){
        const int g = kc >> 8;
        // convert prefetched A + write LDS
        {
            const u16* wa = (const u16*)&pa;
            const u16* wb = (const u16*)&pb;
            float zk = zc3[g][est];
            u16 pk[8];
            #pragma unroll
            for (int i=0;i<8;i++){
                float v = zk * fmaxf(bf2f(wa[i]) + bf2f(wb[i]), 0.f);
                pk[i] = f2bf(v);
            }
            *reinterpret_cast<uint4*>(&Alds[est * 40 + seg * 8]) = *reinterpret_cast<uint4*>(pk);
        }
        #pragma unroll
        for (int i=0;i<4;i++)
            *reinterpret_cast<uint4*>(&Blds[(bn + i*64) * 40 + seg * 8]) = pw[i];
        __syncthreads();
        // issue next iter's loads (latency overlaps MFMA below)
        if (kc + 32 < 768){
            const int kn = kc + 32;
            const int gn = kn >> 8;
            const int jn = (kn & 255) + seg * 8;
            pa = *reinterpret_cast<const uint4*>(&paB[gn * 512 + jn]);
            pb = *reinterpret_cast<const uint4*>(&pbB[gn * 512 + jn]);
            #pragma unroll
            for (int i=0;i<4;i++)
                pw[i] = *reinterpret_cast<const uint4*>(&bwB[(size_t)i * 64 * 768 + kn]);
        }
        bf16x8 af[4], bfr[4];
        #pragma unroll
        for (int r=0;r<4;r++)
            af[r] = *reinterpret_cast<const bf16x8*>(&Alds[(r*16 + l16) * 40 + quad * 8]);
        #pragma unroll
        for (int c=0;c<4;c++)
            bfr[c] = *reinterpret_cast<const bf16x8*>(&Blds[(wave*64 + c*16 + l16) * 40 + quad * 8]);
        #pragma unroll
        for (int r=0;r<4;r++)
            #pragma unroll
            for (int c=0;c<4;c++)
                acc[r][c] = __builtin_amdgcn_mfma_f32_16x16x32_bf16(af[r], bfr[c], acc[r][c], 0, 0, 0);
        __syncthreads();
    }
    // add bias term sum_g z_g*b2[g][col] per (edge,col)
    #pragma unroll
    for (int c=0;c<4;c++){
        int col = wave*64 + c*16 + l16;
        float b20 = b2[col], b21 = b2[256 + col], b22 = b2[512 + col];
        #pragma unroll
        for (int r=0;r<4;r++){
            #pragma unroll
            for (int reg=0;reg<4;reg++){
                int e = r*16 + quad*4 + reg;
                acc[r][c][reg] += zc3[0][e]*b20 + zc3[1][e]*b21 + zc3[2][e]*b22;
            }
        }
    }
    // segment-reduce epilogue (stg aliases staging LDS; safe after last barrier)
    float sum = 0.f;
    int cur_d = -1;
    const int colg = wave*64 + lane;
    #pragma unroll
    for (int chunk = 0; chunk < 2; chunk++){
        #pragma unroll
        for (int rr = 0; rr < 2; rr++){
            int r = chunk*2 + rr;
            #pragma unroll
            for (int c=0;c<4;c++)
                #pragma unroll
                for (int reg=0;reg<4;reg++){
                    int el = rr*16 + quad*4 + reg;
                    stg[wave*(32*65) + el*65 + c*16 + l16] = acc[r][c][reg];
                }
        }
        __syncthreads();
        for (int e = 0; e < 32; e++){
            int eg = chunk*32 + e;
            int dn = dstc[eg];
            float v = stg[wave*(32*65) + e*65 + lane];
            if (dn != cur_d){
                if (cur_d >= 0) atomicAdd(&m_acc[(size_t)cur_d * 256 + colg], sum);
                cur_d = dn; sum = v;
            } else {
                sum += v;
            }
        }
        __syncthreads();
    }
    if (cur_d >= 0) atomicAdd(&m_acc[(size_t)cur_d * 256 + colg], sum);
}

// Fused GRU gates + output head. One block per node (256 threads = 256 hidden).
__global__ void gates_mu_k(
    const float* __restrict__ gh, const u16* __restrict__ m16,
    const float* __restrict__ x, const float* __restrict__ Wih,
    const float* __restrict__ bih, const float* __restrict__ Wo,
    const float* __restrict__ bo, float* __restrict__ prev,
    u16* __restrict__ h16, void* __restrict__ out,
    const int* __restrict__ flag, int t)
{
    const int n = blockIdx.x;
    const int j = threadIdx.x;
    const int idx = n * 256 + j;
    float inp[6];
    if (t < TTEACH){
        #pragma unroll
        for (int c=0;c<6;c++) inp[c] = x[(size_t)n * NFEAT + t * 6 + c];
    } else {
        #pragma unroll
        for (int c=0;c<6;c++) inp[c] = prev[n * 6 + c];
    }
    float m = bf2f(m16[idx]);
    float gxr = bih[j], gxz = bih[256 + j], gxn = bih[512 + j];
    #pragma unroll
    for (int c=0;c<6;c++){
        gxr += inp[c] * Wih[j * 6 + c];
        gxz += inp[c] * Wih[(256 + j) * 6 + c];
        gxn += inp[c] * Wih[(512 + j) * 6 + c];
    }
    float ghr = gh[(size_t)n * 768 + j];
    float ghz = gh[(size_t)n * 768 + 256 + j];
    float ghn = gh[(size_t)n * 768 + 512 + j];
    float r  = 1.f / (1.f + __expf(-(gxr + ghr)));
    float zg = 1.f / (1.f + __expf(-(gxz + ghz)));
    float nn = tanhf(gxn + r * ghn);
    float hv = (1.f - zg) * nn + zg * m;
    h16[idx] = f2bf(hv);
    // output head: mu = inp + relu(h @ Wo + bo)
    __shared__ float hl[256];
    __shared__ float part[6][9];
    hl[j] = hv;
    __syncthreads();
    if (j < 48){
        int c = j >> 3, p = j & 7;
        float s = 0.f;
        #pragma unroll 8
        for (int q = 0; q < 32; q++){
            int jj = p*32 + q;
            s += hl[jj] * Wo[jj * 6 + c];
        }
        part[c][p] = s;
    }
    __syncthreads();
    if (j < 6){
        float s = bo[j];
        #pragma unroll
        for (int p = 0; p < 8; p++) s += part[j][p];
        float mu = inp[j] + fmaxf(s, 0.f);
        if (*flag) ((float*)out)[(size_t)n * NFEAT + t * 6 + j] = mu;
        else       ((u16*)out)[(size_t)n * NFEAT + t * 6 + j] = f2bf(mu);
        prev[n * 6 + j] = mu;
    }
}

extern "C" void kernel_launch(void* const* d_in, const int* in_sizes, int n_in,
                              void* d_out, int out_size, void* d_ws, size_t ws_size,
                              hipStream_t stream)
{
    const void* x_r   = d_in[0];
    const int*  ei    = (const int*)d_in[1];
    const void* z_r   = d_in[2];
    const void* Wf_r  = d_in[3];
    const void* bf_r  = d_in[4];
    const void* W1_r  = d_in[5];
    const void* b1_r  = d_in[6];
    const void* W2_r  = d_in[7];
    const void* b2_r  = d_in[8];
    const void* Wih_r = d_in[9];
    const void* bih_r = d_in[10];
    const void* Whh_r = d_in[11];
    const void* bhh_r = d_in[12];
    const void* Wo_r  = d_in[13];
    const void* bo_r  = d_in[14];

    char* ws = (char*)d_ws;
    size_t off = 0;
    auto alloc = [&](size_t bytes){
        void* p = ws + off;
        off += (bytes + 255) & ~(size_t)255;
        return p;
    };
    u16*   h16   = (u16*)  alloc((size_t)NN * HID * 2);
    float* prev  = (float*)alloc((size_t)NN * 6 * 4);
    u16*   fh16  = (u16*)  alloc((size_t)NN * NFEAT * 2);
    u16*   AB16  = (u16*)  alloc((size_t)NN * 1536 * 2);
    float* m_acc = (float*)alloc((size_t)NN * HID * 4);
    u16*   m16   = (u16*)  alloc((size_t)NN * HID * 2);
    float* gh    = (float*)alloc((size_t)NN * 768 * 4);
    float* invc  = (float*)alloc((size_t)NN * 4);
    int*   cnt   = (int*)  alloc((size_t)NN * 4);
    int*   binoff= (int*)  alloc((size_t)(NN + 1) * 4);
    int*   curw  = (int*)  alloc((size_t)NN * 4);
    u16*   WfT   = (u16*)  alloc((size_t)192 * 256 * 2);
    u16*   W1T   = (u16*)  alloc((size_t)1536 * 192 * 2);
    u16*   Whh16 = (u16*)  alloc((size_t)768 * 256 * 2);
    u16*   W2T   = (u16*)  alloc((size_t)256 * 768 * 2);
    int*   src32 = (int*)  alloc((size_t)NE * 4);
    int*   dst32 = (int*)  alloc((size_t)NE * 4);
    int*   srcS  = (int*)  alloc((size_t)NE * 4);
    int*   dstS  = (int*)  alloc((size_t)NE * 4);
    float* zS    = (float*)alloc((size_t)3 * NE * 4);
    int*   fdt   = (int*)  alloc(256);
    int*   fidx  = (int*)  alloc(256);
    float* xc   = (float*)alloc((size_t)NN * NFEAT * 4);
    float* zc   = (float*)alloc((size_t)NE * 4 * 4);
    float* Wfc  = (float*)alloc((size_t)256 * 192 * 4);
    float* bfc  = (float*)alloc(192 * 4);
    float* W1c  = (float*)alloc((size_t)3 * 384 * 256 * 4);
    float* b1c  = (float*)alloc(768 * 4);
    float* W2c  = (float*)alloc((size_t)3 * 256 * 256 * 4);
    float* b2c  = (float*)alloc(768 * 4);
    float* Wihc = (float*)alloc((size_t)768 * 6 * 4);
    float* bihc = (float*)alloc(768 * 4);
    float* Whhc = (float*)alloc((size_t)768 * 256 * 4);
    float* bhhc = (float*)alloc(768 * 4);
    float* Woc  = (float*)alloc((size_t)256 * 6 * 4);
    float* boc  = (float*)alloc(6 * 4);

    detect_f32<<<1, 1, 0, stream>>>((const u16*)z_r, fdt);
    detect_i64<<<1, 1, 0, stream>>>(ei, fidx);
    copy_edges<<<(NE + 255)/256, 256, 0, stream>>>(ei, fidx, src32, dst32);

    auto conv = [&](const void* in, float* outp, int n){
        conv_f32<<<(n + 255)/256, 256, 0, stream>>>(in, outp, n, fdt);
    };
    conv(x_r,   xc,   NN * NFEAT);
    conv(z_r,   zc,   NE * 4);
    conv(Wf_r,  Wfc,  256 * 192);
    conv(bf_r,  bfc,  192);
    conv(W1_r,  W1c,  3 * 384 * 256);
    conv(b1_r,  b1c,  768);
    conv(W2_r,  W2c,  3 * 256 * 256);
    conv(b2_r,  b2c,  768);
    conv(Wih_r, Wihc, 768 * 6);
    conv(bih_r, bihc, 768);
    conv(Whh_r, Whhc, 768 * 256);
    conv(bhh_r, bhhc, 768);
    conv(Wo_r,  Woc,  256 * 6);
    conv(bo_r,  boc,  6);

    fill_f32<<<(NN*HID/2 + 255)/256, 256, 0, stream>>>((float*)h16, 0.f, NN*HID/2);
    fill_f32<<<(NN*6 + 255)/256, 256, 0, stream>>>(prev, 0.f, NN*6);
    fill_f32<<<(NN*HID + 255)/256, 256, 0, stream>>>(m_acc, 0.f, NN*HID);
    fill_i32<<<(NN + 255)/256, 256, 0, stream>>>(cnt, 0, NN);
    degree_k<<<(NE + 255)/256, 256, 0, stream>>>(dst32, cnt, NE);
    invcnt_k<<<(NN + 255)/256, 256, 0, stream>>>(cnt, invc, NN);
    scan_k<<<1, 1024, 0, stream>>>(cnt, binoff);
    copy_i32<<<(NN + 255)/256, 256, 0, stream>>>(binoff, curw, NN);
    scatter_k<<<(NE + 255)/256, 256, 0, stream>>>(src32, dst32, zc, curw, srcS, dstS, zS);
    build_wft<<<(256*192 + 255)/256, 256, 0, stream>>>(Wfc, WfT);
    build_w1t<<<(1536*192 + 255)/256, 256, 0, stream>>>(W1c, W1T);
    conv_bf16<<<(768*256 + 255)/256, 256, 0, stream>>>(Whhc, Whh16, 768*256);
    build_w2t<<<(768*256 + 255)/256, 256, 0, stream>>>(W2c, W2T);

    for (int t = 0; t < TS; t++){
        gemm_mfma<0><<<dim3(40, 3), 256, 0, stream>>>(h16, WfT, bfc, nullptr, fh16, NN, 256, NFEAT);
        gemm_mfma<1><<<dim3(40, 24), 256, 0, stream>>>(fh16, W1T, b1c, nullptr, AB16, NN, NFEAT, 1536);
        edge_mfma<<<2500, 256, 0, stream>>>(AB16, W2T, b2c, zS, srcS, dstS, m_acc);
        mscale_k<<<(NN*HID + 255)/256, 256, 0, stream>>>(m_acc, invc, m16);
        gemm_mfma<2><<<dim3(40, 12), 256, 0, stream>>>(m16, Whh16, bhhc, gh, nullptr, NN, 256, 768);
        gates_mu_k<<<NN, 256, 0, stream>>>(gh, m16, xc, Wihc, bihc, Woc, boc, prev, h16, d_out, fdt, t);
    }
}

// Round 9
// 7231.198 us; speedup vs baseline: 1.7555x; 1.7555x over previous
//
#include <hip/hip_runtime.h>
#include <hip/hip_bf16.h>

#define NN 10000      // nodes
#define NE 160000     // edges
#define TS 32         // timesteps
#define HID 256
#define NFEAT 192
#define TTEACH 24

typedef unsigned short u16;
typedef unsigned int u32;
typedef __attribute__((ext_vector_type(8))) short bf16x8;
typedef __attribute__((ext_vector_type(4))) float f32x4;

__device__ __forceinline__ float bf2f(u16 u){
    u32 v = ((u32)u) << 16;
    union { u32 i; float f; } c; c.i = v; return c.f;
}
__device__ __forceinline__ u16 f2bf(float f){
    union { float f; u32 i; } c; c.f = f;
    u32 i = c.i;
    u32 lsb = (i >> 16) & 1u;
    i += 0x7fffu + lsb;
    return (u16)(i >> 16);
}

__global__ void fill_f32(float* p, float v, int n){
    int i = blockIdx.x * 256 + threadIdx.x;
    if (i < n) p[i] = v;
}
__global__ void fill_i32(int* p, int v, int n){
    int i = blockIdx.x * 256 + threadIdx.x;
    if (i < n) p[i] = v;
}
__global__ void copy_i32(const int* __restrict__ a, int* __restrict__ b, int n){
    int i = blockIdx.x * 256 + threadIdx.x;
    if (i < n) b[i] = a[i];
}

// ---------- runtime dtype detection ----------
__global__ void detect_f32(const u16* __restrict__ zraw, int* __restrict__ flag){
    int c = 0;
    for (int i = 0; i < 128; i++) if (zraw[2*i] >= 0x4000) c++;
    *flag = (c > 8) ? 1 : 0;
}
__global__ void conv_f32(const void* __restrict__ in, float* __restrict__ outp,
                         int n, const int* __restrict__ flag){
    int i = blockIdx.x * 256 + threadIdx.x;
    if (i >= n) return;
    if (*flag) outp[i] = ((const float*)in)[i];
    else       outp[i] = bf2f(((const u16*)in)[i]);
}
__global__ void detect_i64(const int* __restrict__ ei_raw, int* __restrict__ flag){
    int zz = 0;
    #pragma unroll
    for (int i = 0; i < 32; i++) zz |= ei_raw[2*i + 1];
    *flag = (zz == 0) ? 1 : 0;
}
__global__ void copy_edges(const int* __restrict__ ei_raw, const int* __restrict__ flag,
                           int* __restrict__ src, int* __restrict__ dst){
    int e = blockIdx.x * 256 + threadIdx.x;
    if (e >= NE) return;
    int st = (*flag) ? 2 : 1;
    src[e] = ei_raw[(size_t)e * st];
    dst[e] = ei_raw[((size_t)NE + e) * st];
}

__global__ void degree_k(const int* __restrict__ dst, int* __restrict__ cnt, int n){
    int e = blockIdx.x * 256 + threadIdx.x;
    if (e < n) atomicAdd(&cnt[dst[e]], 1);
}
__global__ void invcnt_k(const int* __restrict__ cnt, float* __restrict__ inv, int n){
    int i = blockIdx.x * 256 + threadIdx.x;
    if (i < n) inv[i] = 1.0f / fmaxf((float)cnt[i], 1.0f);
}

// exclusive scan of cnt[10000] -> binoff[10000], single block 1024 threads
__global__ void scan_k(const int* __restrict__ cnt, int* __restrict__ binoff){
    __shared__ int ps[1024];
    int t = threadIdx.x;
    int s = 0;
    if (t < 1000)
        for (int i = 0; i < 10; i++) s += cnt[t*10 + i];
    ps[t] = s;
    __syncthreads();
    for (int ofs = 1; ofs < 1024; ofs <<= 1){
        int v = (t >= ofs) ? ps[t - ofs] : 0;
        __syncthreads();
        ps[t] += v;
        __syncthreads();
    }
    if (t < 1000){
        int run = (t == 0) ? 0 : ps[t-1];
        for (int i = 0; i < 10; i++){
            binoff[t*10 + i] = run;
            run += cnt[t*10 + i];
        }
    }
}
// scatter edges into dst-sorted order; builds sorted src/dst and z planes
__global__ void scatter_k(const int* __restrict__ src32, const int* __restrict__ dst32,
                          const float* __restrict__ zc, int* __restrict__ cur,
                          int* __restrict__ srcS, int* __restrict__ dstS,
                          float* __restrict__ zS){
    int e = blockIdx.x * 256 + threadIdx.x;
    if (e >= NE) return;
    int d = dst32[e];
    int pos = atomicAdd(&cur[d], 1);
    srcS[pos] = src32[e];
    dstS[pos] = d;
    zS[pos]        = zc[(size_t)e*4 + 1];
    zS[NE + pos]   = zc[(size_t)e*4 + 2];
    zS[2*NE + pos] = zc[(size_t)e*4 + 3];
}

// WfT[n][k] = Wf[k][n] bf16  (Wf: [256][192])
__global__ void build_wft(const float* __restrict__ Wfc, u16* __restrict__ WfT){
    int idx = blockIdx.x * 256 + threadIdx.x;
    if (idx < 256 * 192){
        int k = idx / 192, n = idx % 192;
        WfT[(size_t)n * 256 + k] = f2bf(Wfc[idx]);
    }
}
// W1T[n][k] bf16, n in [0,1536): kblk=n>>9, part=(n>>8)&1, c=n&255; k in [0,192)
__global__ void build_w1t(const float* __restrict__ W1c, u16* __restrict__ W1T){
    int idx = blockIdx.x * 256 + threadIdx.x;
    if (idx < 1536 * 192){
        int n = idx / 192, k = idx % 192;
        int kblk = n >> 9, part = (n >> 8) & 1, c = n & 255;
        W1T[idx] = f2bf(W1c[(size_t)kblk * (384*256) + (size_t)(part*192 + k) * 256 + c]);
    }
}
__global__ void conv_bf16(const float* __restrict__ in, u16* __restrict__ outp, int n){
    int i = blockIdx.x * 256 + threadIdx.x;
    if (i < n) outp[i] = f2bf(in[i]);
}
// W2T[n][k] = W2[k][n] bf16; W2 flat [768][256] fp32
__global__ void build_w2t(const float* __restrict__ W2c, u16* __restrict__ W2T){
    int idx = blockIdx.x * 256 + threadIdx.x;
    if (idx < 768 * 256){
        int k = idx / 256, n = idx % 256;
        W2T[(size_t)n * 768 + k] = f2bf(W2c[idx]);
    }
}
// m16 = bf16(m_acc * inv); also re-zeros m_acc for the next step's atomics
__global__ void mscale_k(float* __restrict__ m_acc, const float* __restrict__ inv,
                         u16* __restrict__ m16){
    int idx = blockIdx.x * 256 + threadIdx.x;
    if (idx < NN * HID){
        m16[idx] = f2bf(m_acc[idx] * inv[idx >> 8]);
        m_acc[idx] = 0.f;
    }
}

// ---------------- MFMA node GEMM ----------------
// C[M,N] = epi(A16[M,K] @ BT16[N,K]^T + bias)
// MODE 0: +bias, relu, out bf16 | MODE 1: +b1 if part==0, out bf16 | MODE 2: +bias, out fp32
template<int MODE>
__global__ __launch_bounds__(256, 2) void gemm_mfma(
    const u16* __restrict__ A16, const u16* __restrict__ BT16,
    const float* __restrict__ bias, float* __restrict__ Cf, u16* __restrict__ Cb,
    int M, int Kd, int Nd)
{
    __shared__ __align__(16) u16 Alds[256 * 40];
    __shared__ __align__(16) u16 Blds[64 * 40];
    const int tid = threadIdx.x;
    const int m0 = blockIdx.x * 256;
    const int n0 = blockIdx.y * 64;
    const int wave = tid >> 6, lane = tid & 63;
    const int quad = lane >> 4, l16 = lane & 15;

    const f32x4 zero4 = {0.f, 0.f, 0.f, 0.f};
    f32x4 acc[4][4];
    #pragma unroll
    for (int r=0;r<4;r++)
        #pragma unroll
        for (int c=0;c<4;c++) acc[r][c] = zero4;

    const int arow = m0 + tid;
    const u16* ap = &A16[(size_t)arow * Kd];
    const int bn = tid >> 2, bseg = tid & 3;
    const u16* bp = &BT16[(size_t)(n0 + bn) * Kd + bseg * 8];

    for (int k0 = 0; k0 < Kd; k0 += 32){
        if (arow < M){
            const uint4* q = reinterpret_cast<const uint4*>(ap + k0);
            uint4 v0 = q[0], v1 = q[1], v2 = q[2], v3 = q[3];
            *reinterpret_cast<uint4*>(&Alds[tid * 40])      = v0;
            *reinterpret_cast<uint4*>(&Alds[tid * 40 + 8])  = v1;
            *reinterpret_cast<uint4*>(&Alds[tid * 40 + 16]) = v2;
            *reinterpret_cast<uint4*>(&Alds[tid * 40 + 24]) = v3;
        } else {
            uint4 zz = {0,0,0,0};
            #pragma unroll
            for (int s=0;s<4;s++)
                *reinterpret_cast<uint4*>(&Alds[tid * 40 + s*8]) = zz;
        }
        {
            uint4 v = *reinterpret_cast<const uint4*>(bp + k0);
            *reinterpret_cast<uint4*>(&Blds[bn * 40 + bseg * 8]) = v;
        }
        __syncthreads();
        bf16x8 af[4], bfr[4];
        #pragma unroll
        for (int r=0;r<4;r++)
            af[r] = *reinterpret_cast<const bf16x8*>(&Alds[(wave*64 + r*16 + l16) * 40 + quad * 8]);
        #pragma unroll
        for (int c=0;c<4;c++)
            bfr[c] = *reinterpret_cast<const bf16x8*>(&Blds[(c*16 + l16) * 40 + quad * 8]);
        #pragma unroll
        for (int r=0;r<4;r++)
            #pragma unroll
            for (int c=0;c<4;c++)
                acc[r][c] = __builtin_amdgcn_mfma_f32_16x16x32_bf16(af[r], bfr[c], acc[r][c], 0, 0, 0);
        __syncthreads();
    }
    #pragma unroll
    for (int c=0;c<4;c++){
        int col = n0 + c*16 + l16;
        float bv = 0.f;
        if (MODE == 0 || MODE == 2) bv = bias[col];
        if (MODE == 1){
            int part = (col >> 8) & 1;
            if (part == 0) bv = bias[(col >> 9) * 256 + (col & 255)];
        }
        #pragma unroll
        for (int r=0;r<4;r++){
            #pragma unroll
            for (int reg=0;reg<4;reg++){
                int row = m0 + wave*64 + r*16 + quad*4 + reg;
                if (row >= M) continue;
                float v = acc[r][c][reg] + bv;
                if (MODE == 0) v = fmaxf(v, 0.f);
                if (MODE == 2) Cf[(size_t)row * Nd + col] = v;
                else           Cb[(size_t)row * Nd + col] = f2bf(v);
            }
        }
    }
}

// MFMA edge kernel on dst-sorted edges: 64 edges x 256 cols per block, K=768.
// LDS: stg aliases Alds+Blds (disjoint lifetimes) -> 34.8 KB, 4 blocks/CU.
// Register prefetch of the two random gathers only (W2T is L2-hot, loads in-loop).
// launch_bounds(256,2): do NOT clamp VGPR below the ~100-reg working set (r8 spill).
__global__ __launch_bounds__(256, 2) void edge_mfma(
    const u16* __restrict__ AB16, const u16* __restrict__ W2T,
    const float* __restrict__ b2, const float* __restrict__ zS,
    const int* __restrict__ srcS, const int* __restrict__ dstS,
    float* __restrict__ m_acc)
{
    __shared__ __align__(16) char smem[33280];      // max(Alds 5120 + Blds 20480, stg 33280)
    u16*   Alds = (u16*)smem;                        // [64 rows][40 u16]
    u16*   Blds = (u16*)(smem + 5120);               // [256 rows][40 u16]
    float* stg  = (float*)smem;                      // [4][32][65] epilogue alias
    __shared__ float zc3[3][64];
    __shared__ int dstc[64], srcc[64];
    const int tid = threadIdx.x;
    const int eb = blockIdx.x * 64;

    if (tid < 64){
        srcc[tid] = srcS[eb + tid];
        dstc[tid] = dstS[eb + tid];
    }
    int tz = tid - 64;
    if (tz >= 0 && tz < 192){
        int g = tz / 64, e = tz % 64;
        zc3[g][e] = zS[(size_t)g * NE + eb + e];
    }
    __syncthreads();

    const int wave = tid >> 6, lane = tid & 63;
    const int quad = lane >> 4, l16 = lane & 15;
    const int est = tid >> 2, seg = tid & 3;

    const f32x4 zero4 = {0.f, 0.f, 0.f, 0.f};
    f32x4 acc[4][4];
    #pragma unroll
    for (int r=0;r<4;r++)
        #pragma unroll
        for (int c=0;c<4;c++) acc[r][c] = zero4;

    const int d = dstc[est], s = srcc[est];
    const u16* paB = &AB16[(size_t)d * 1536];         // + g*512 + j0
    const u16* pbB = &AB16[(size_t)s * 1536 + 256];
    const int bn = tid >> 2;
    const u16* bwB = &W2T[(size_t)bn * 768 + seg * 8];// rows bn + i*64

    // prefetch iter 0 gathers
    uint4 pa = *reinterpret_cast<const uint4*>(&paB[seg * 8]);
    uint4 pb = *reinterpret_cast<const uint4*>(&pbB[seg * 8]);

    for (int kc = 0; kc < 768; kc += 32){
        const int g = kc >> 8;
        // convert prefetched A + write LDS
        {
            const u16* wa = (const u16*)&pa;
            const u16* wb = (const u16*)&pb;
            float zk = zc3[g][est];
            u16 pk[8];
            #pragma unroll
            for (int i=0;i<8;i++){
                float v = zk * fmaxf(bf2f(wa[i]) + bf2f(wb[i]), 0.f);
                pk[i] = f2bf(v);
            }
            *reinterpret_cast<uint4*>(&Alds[est * 40 + seg * 8]) = *reinterpret_cast<uint4*>(pk);
        }
        // stage B (L2-hot streaming loads, no prefetch)
        #pragma unroll
        for (int i=0;i<4;i++){
            uint4 w = *reinterpret_cast<const uint4*>(&bwB[(size_t)i * 64 * 768 + kc]);
            *reinterpret_cast<uint4*>(&Blds[(bn + i*64) * 40 + seg * 8]) = w;
        }
        __syncthreads();
        // issue next iter's gathers (latency overlaps MFMA below)
        if (kc + 32 < 768){
            const int kn = kc + 32;
            const int gn = kn >> 8;
            const int jn = (kn & 255) + seg * 8;
            pa = *reinterpret_cast<const uint4*>(&paB[gn * 512 + jn]);
            pb = *reinterpret_cast<const uint4*>(&pbB[gn * 512 + jn]);
        }
        bf16x8 af[4], bfr[4];
        #pragma unroll
        for (int r=0;r<4;r++)
            af[r] = *reinterpret_cast<const bf16x8*>(&Alds[(r*16 + l16) * 40 + quad * 8]);
        #pragma unroll
        for (int c=0;c<4;c++)
            bfr[c] = *reinterpret_cast<const bf16x8*>(&Blds[(wave*64 + c*16 + l16) * 40 + quad * 8]);
        #pragma unroll
        for (int r=0;r<4;r++)
            #pragma unroll
            for (int c=0;c<4;c++)
                acc[r][c] = __builtin_amdgcn_mfma_f32_16x16x32_bf16(af[r], bfr[c], acc[r][c], 0, 0, 0);
        __syncthreads();
    }
    // add bias term sum_g z_g*b2[g][col] per (edge,col)
    #pragma unroll
    for (int c=0;c<4;c++){
        int col = wave*64 + c*16 + l16;
        float b20 = b2[col], b21 = b2[256 + col], b22 = b2[512 + col];
        #pragma unroll
        for (int r=0;r<4;r++){
            #pragma unroll
            for (int reg=0;reg<4;reg++){
                int e = r*16 + quad*4 + reg;
                acc[r][c][reg] += zc3[0][e]*b20 + zc3[1][e]*b21 + zc3[2][e]*b22;
            }
        }
    }
    // segment-reduce epilogue (stg aliases staging LDS; safe after last barrier)
    float sum = 0.f;
    int cur_d = -1;
    const int colg = wave*64 + lane;
    #pragma unroll
    for (int chunk = 0; chunk < 2; chunk++){
        #pragma unroll
        for (int rr = 0; rr < 2; rr++){
            int r = chunk*2 + rr;
            #pragma unroll
            for (int c=0;c<4;c++)
                #pragma unroll
                for (int reg=0;reg<4;reg++){
                    int el = rr*16 + quad*4 + reg;
                    stg[wave*(32*65) + el*65 + c*16 + l16] = acc[r][c][reg];
                }
        }
        __syncthreads();
        for (int e = 0; e < 32; e++){
            int eg = chunk*32 + e;
            int dn = dstc[eg];
            float v = stg[wave*(32*65) + e*65 + lane];
            if (dn != cur_d){
                if (cur_d >= 0) atomicAdd(&m_acc[(size_t)cur_d * 256 + colg], sum);
                cur_d = dn; sum = v;
            } else {
                sum += v;
            }
        }
        __syncthreads();
    }
    if (cur_d >= 0) atomicAdd(&m_acc[(size_t)cur_d * 256 + colg], sum);
}

// Fused GRU gates + output head. One block per node (256 threads = 256 hidden).
__global__ void gates_mu_k(
    const float* __restrict__ gh, const u16* __restrict__ m16,
    const float* __restrict__ x, const float* __restrict__ Wih,
    const float* __restrict__ bih, const float* __restrict__ Wo,
    const float* __restrict__ bo, float* __restrict__ prev,
    u16* __restrict__ h16, void* __restrict__ out,
    const int* __restrict__ flag, int t)
{
    const int n = blockIdx.x;
    const int j = threadIdx.x;
    const int idx = n * 256 + j;
    float inp[6];
    if (t < TTEACH){
        #pragma unroll
        for (int c=0;c<6;c++) inp[c] = x[(size_t)n * NFEAT + t * 6 + c];
    } else {
        #pragma unroll
        for (int c=0;c<6;c++) inp[c] = prev[n * 6 + c];
    }
    float m = bf2f(m16[idx]);
    float gxr = bih[j], gxz = bih[256 + j], gxn = bih[512 + j];
    #pragma unroll
    for (int c=0;c<6;c++){
        gxr += inp[c] * Wih[j * 6 + c];
        gxz += inp[c] * Wih[(256 + j) * 6 + c];
        gxn += inp[c] * Wih[(512 + j) * 6 + c];
    }
    float ghr = gh[(size_t)n * 768 + j];
    float ghz = gh[(size_t)n * 768 + 256 + j];
    float ghn = gh[(size_t)n * 768 + 512 + j];
    float r  = 1.f / (1.f + __expf(-(gxr + ghr)));
    float zg = 1.f / (1.f + __expf(-(gxz + ghz)));
    float nn = tanhf(gxn + r * ghn);
    float hv = (1.f - zg) * nn + zg * m;
    h16[idx] = f2bf(hv);
    // output head: mu = inp + relu(h @ Wo + bo)
    __shared__ float hl[256];
    __shared__ float part[6][9];
    hl[j] = hv;
    __syncthreads();
    if (j < 48){
        int c = j >> 3, p = j & 7;
        float s = 0.f;
        #pragma unroll 8
        for (int q = 0; q < 32; q++){
            int jj = p*32 + q;
            s += hl[jj] * Wo[jj * 6 + c];
        }
        part[c][p] = s;
    }
    __syncthreads();
    if (j < 6){
        float s = bo[j];
        #pragma unroll
        for (int p = 0; p < 8; p++) s += part[j][p];
        float mu = inp[j] + fmaxf(s, 0.f);
        if (*flag) ((float*)out)[(size_t)n * NFEAT + t * 6 + j] = mu;
        else       ((u16*)out)[(size_t)n * NFEAT + t * 6 + j] = f2bf(mu);
        prev[n * 6 + j] = mu;
    }
}

extern "C" void kernel_launch(void* const* d_in, const int* in_sizes, int n_in,
                              void* d_out, int out_size, void* d_ws, size_t ws_size,
                              hipStream_t stream)
{
    const void* x_r   = d_in[0];
    const int*  ei    = (const int*)d_in[1];
    const void* z_r   = d_in[2];
    const void* Wf_r  = d_in[3];
    const void* bf_r  = d_in[4];
    const void* W1_r  = d_in[5];
    const void* b1_r  = d_in[6];
    const void* W2_r  = d_in[7];
    const void* b2_r  = d_in[8];
    const void* Wih_r = d_in[9];
    const void* bih_r = d_in[10];
    const void* Whh_r = d_in[11];
    const void* bhh_r = d_in[12];
    const void* Wo_r  = d_in[13];
    const void* bo_r  = d_in[14];

    char* ws = (char*)d_ws;
    size_t off = 0;
    auto alloc = [&](size_t bytes){
        void* p = ws + off;
        off += (bytes + 255) & ~(size_t)255;
        return p;
    };
    u16*   h16   = (u16*)  alloc((size_t)NN * HID * 2);
    float* prev  = (float*)alloc((size_t)NN * 6 * 4);
    u16*   fh16  = (u16*)  alloc((size_t)NN * NFEAT * 2);
    u16*   AB16  = (u16*)  alloc((size_t)NN * 1536 * 2);
    float* m_acc = (float*)alloc((size_t)NN * HID * 4);
    u16*   m16   = (u16*)  alloc((size_t)NN * HID * 2);
    float* gh    = (float*)alloc((size_t)NN * 768 * 4);
    float* invc  = (float*)alloc((size_t)NN * 4);
    int*   cnt   = (int*)  alloc((size_t)NN * 4);
    int*   binoff= (int*)  alloc((size_t)(NN + 1) * 4);
    int*   curw  = (int*)  alloc((size_t)NN * 4);
    u16*   WfT   = (u16*)  alloc((size_t)192 * 256 * 2);
    u16*   W1T   = (u16*)  alloc((size_t)1536 * 192 * 2);
    u16*   Whh16 = (u16*)  alloc((size_t)768 * 256 * 2);
    u16*   W2T   = (u16*)  alloc((size_t)256 * 768 * 2);
    int*   src32 = (int*)  alloc((size_t)NE * 4);
    int*   dst32 = (int*)  alloc((size_t)NE * 4);
    int*   srcS  = (int*)  alloc((size_t)NE * 4);
    int*   dstS  = (int*)  alloc((size_t)NE * 4);
    float* zS    = (float*)alloc((size_t)3 * NE * 4);
    int*   fdt   = (int*)  alloc(256);
    int*   fidx  = (int*)  alloc(256);
    float* xc   = (float*)alloc((size_t)NN * NFEAT * 4);
    float* zc   = (float*)alloc((size_t)NE * 4 * 4);
    float* Wfc  = (float*)alloc((size_t)256 * 192 * 4);
    float* bfc  = (float*)alloc(192 * 4);
    float* W1c  = (float*)alloc((size_t)3 * 384 * 256 * 4);
    float* b1c  = (float*)alloc(768 * 4);
    float* W2c  = (float*)alloc((size_t)3 * 256 * 256 * 4);
    float* b2c  = (float*)alloc(768 * 4);
    float* Wihc = (float*)alloc((size_t)768 * 6 * 4);
    float* bihc = (float*)alloc(768 * 4);
    float* Whhc = (float*)alloc((size_t)768 * 256 * 4);
    float* bhhc = (float*)alloc(768 * 4);
    float* Woc  = (float*)alloc((size_t)256 * 6 * 4);
    float* boc  = (float*)alloc(6 * 4);

    detect_f32<<<1, 1, 0, stream>>>((const u16*)z_r, fdt);
    detect_i64<<<1, 1, 0, stream>>>(ei, fidx);
    copy_edges<<<(NE + 255)/256, 256, 0, stream>>>(ei, fidx, src32, dst32);

    auto conv = [&](const void* in, float* outp, int n){
        conv_f32<<<(n + 255)/256, 256, 0, stream>>>(in, outp, n, fdt);
    };
    conv(x_r,   xc,   NN * NFEAT);
    conv(z_r,   zc,   NE * 4);
    conv(Wf_r,  Wfc,  256 * 192);
    conv(bf_r,  bfc,  192);
    conv(W1_r,  W1c,  3 * 384 * 256);
    conv(b1_r,  b1c,  768);
    conv(W2_r,  W2c,  3 * 256 * 256);
    conv(b2_r,  b2c,  768);
    conv(Wih_r, Wihc, 768 * 6);
    conv(bih_r, bihc, 768);
    conv(Whh_r, Whhc, 768 * 256);
    conv(bhh_r, bhhc, 768);
    conv(Wo_r,  Woc,  256 * 6);
    conv(bo_r,  boc,  6);

    fill_f32<<<(NN*HID/2 + 255)/256, 256, 0, stream>>>((float*)h16, 0.f, NN*HID/2);
    fill_f32<<<(NN*6 + 255)/256, 256, 0, stream>>>(prev, 0.f, NN*6);
    fill_f32<<<(NN*HID + 255)/256, 256, 0, stream>>>(m_acc, 0.f, NN*HID);
    fill_i32<<<(NN + 255)/256, 256, 0, stream>>>(cnt, 0, NN);
    degree_k<<<(NE + 255)/256, 256, 0, stream>>>(dst32, cnt, NE);
    invcnt_k<<<(NN + 255)/256, 256, 0, stream>>>(cnt, invc, NN);
    scan_k<<<1, 1024, 0, stream>>>(cnt, binoff);
    copy_i32<<<(NN + 255)/256, 256, 0, stream>>>(binoff, curw, NN);
    scatter_k<<<(NE + 255)/256, 256, 0, stream>>>(src32, dst32, zc, curw, srcS, dstS, zS);
    build_wft<<<(256*192 + 255)/256, 256, 0, stream>>>(Wfc, WfT);
    build_w1t<<<(1536*192 + 255)/256, 256, 0, stream>>>(W1c, W1T);
    conv_bf16<<<(768*256 + 255)/256, 256, 0, stream>>>(Whhc, Whh16, 768*256);
    build_w2t<<<(768*256 + 255)/256, 256, 0, stream>>>(W2c, W2T);

    for (int t = 0; t < TS; t++){
        gemm_mfma<0><<<dim3(40, 3), 256, 0, stream>>>(h16, WfT, bfc, nullptr, fh16, NN, 256, NFEAT);
        gemm_mfma<1><<<dim3(40, 24), 256, 0, stream>>>(fh16, W1T, b1c, nullptr, AB16, NN, NFEAT, 1536);
        edge_mfma<<<2500, 256, 0, stream>>>(AB16, W2T, b2c, zS, srcS, dstS, m_acc);
        mscale_k<<<(NN*HID + 255)/256, 256, 0, stream>>>(m_acc, invc, m16);
        gemm_mfma<2><<<dim3(40, 12), 256, 0, stream>>>(m16, Whh16, bhhc, gh, nullptr, NN, 256, 768);
        gates_mu_k<<<NN, 256, 0, stream>>>(gh, m16, xc, Wihc, bihc, Woc, boc, prev, h16, d_out, fdt, t);
    }
}